// Round 1
// baseline (361.359 us; speedup 1.0000x reference)
//
#include <hip/hip_runtime.h>
#include <cstdint>

namespace {

constexpr int W = 256;
constexpr int ITERS = 10;

// One block per (n,h) matrix. 1024 threads; thread (tr=tid>>5, tc=tid&31)
// owns the 8x8 tile rows [8tr,8tr+8) x cols [8tc,8tc+8) of E = exp(attn),
// kept in registers for all 10 Sinkhorn iterations (exp-domain recursion:
// no transcendentals after the initial exp).
__global__ __launch_bounds__(1024, 4) void sinkhorn_disp_kernel(
    const float* __restrict__ attn,
    const float* __restrict__ phi_p,
    float* __restrict__ out,
    int nh)
{
  // partial buffer: 32 partials per column/row. float stride 260 so that the
  // two tr-halves of a wave hit disjoint bank sets on ds_write_b128.
  __shared__ union {
    float f[32][260];                 // GEMV partials (33,280 B)
    unsigned long long a[32][257];    // argmax partials (65,792 B)
  } part;
  __shared__ float eu[W + 1];
  __shared__ float ev[W + 1];
  __shared__ float win[W][4];
  __shared__ int   jmax[W];
  __shared__ float Seu_s, Sev_s, ephi_s;

  const int tid = threadIdx.x;
  const int tc  = tid & 31;
  const int tr  = tid >> 5;
  const int bid = blockIdx.x;

  // ---- load + exp (the only big HBM traffic: 256 KB/block) ----
  float E[8][8];
  {
    const float* src = attn + (size_t)bid * (W * W) + (size_t)(tr * 8) * W + tc * 8;
    #pragma unroll
    for (int a = 0; a < 8; ++a) {
      float4 x0 = *(const float4*)(src + a * W);
      float4 x1 = *(const float4*)(src + a * W + 4);
      E[a][0] = __expf(x0.x); E[a][1] = __expf(x0.y);
      E[a][2] = __expf(x0.z); E[a][3] = __expf(x0.w);
      E[a][4] = __expf(x1.x); E[a][5] = __expf(x1.y);
      E[a][6] = __expf(x1.z); E[a][7] = __expf(x1.w);
    }
  }
  if (tid <= W) eu[tid] = 1.0f;          // u0 = 0  -> eu = 1
  if (tid == 0) ephi_s = __expf(phi_p[0]);
  __syncthreads();

  const float inv2w = 1.0f / (2.0f * W); // mu_i = nu_i = 1/(2W) for i<W; 0.5 at dustbin

  for (int it = 0; it < ITERS; ++it) {
    // ---- column pass partials: cp[b] = sum_a E[a][b] * eu[8tr+a] ----
    {
      float cp[8];
      #pragma unroll
      for (int b = 0; b < 8; ++b) cp[b] = 0.0f;
      #pragma unroll
      for (int a = 0; a < 8; ++a) {
        float eua = eu[tr * 8 + a];      // broadcast LDS read
        #pragma unroll
        for (int b = 0; b < 8; ++b) cp[b] = __builtin_fmaf(E[a][b], eua, cp[b]);
      }
      float4* dst = (float4*)&part.f[tr][tc * 8];
      dst[0] = make_float4(cp[0], cp[1], cp[2], cp[3]);
      dst[1] = make_float4(cp[4], cp[5], cp[6], cp[7]);
    }
    // wave 0 (concurrently): Seu = sum_{i<=W} eu_i (for dustbin column)
    if (tid < 64) {
      float s = eu[tid] + eu[tid + 64] + eu[tid + 128] + eu[tid + 192];
      if (tid == 0) s += eu[W];
      #pragma unroll
      for (int off = 32; off > 0; off >>= 1) s += __shfl_xor(s, off, 64);
      if (tid == 0) Seu_s = s;
    }
    __syncthreads();
    // ---- column finalize: ev_j = nu_j / colsum_j ----
    if (tid < W) {
      float s = 0.0f;
      #pragma unroll
      for (int r = 0; r < 32; ++r) s += part.f[r][tid];   // stride-1, conflict-free
      s += ephi_s * eu[W];                                // dustbin row contribution
      ev[tid] = inv2w / s;
    } else if (tid == W) {
      ev[W] = 0.5f / (ephi_s * Seu_s);                    // dustbin column
    }
    __syncthreads();
    // ---- row pass partials: rp[a] = sum_b E[a][b] * ev[8tc+b] ----
    {
      float rp[8];
      #pragma unroll
      for (int a = 0; a < 8; ++a) rp[a] = 0.0f;
      #pragma unroll
      for (int b = 0; b < 8; ++b) {
        float evb = ev[tc * 8 + b];
        #pragma unroll
        for (int a = 0; a < 8; ++a) rp[a] = __builtin_fmaf(E[a][b], evb, rp[a]);
      }
      float4* dst = (float4*)&part.f[tc][tr * 8];
      dst[0] = make_float4(rp[0], rp[1], rp[2], rp[3]);
      dst[1] = make_float4(rp[4], rp[5], rp[6], rp[7]);
    }
    // wave 0: Sev = sum_{j<=W} ev_j (for dustbin row)
    if (tid < 64) {
      float s = ev[tid] + ev[tid + 64] + ev[tid + 128] + ev[tid + 192];
      if (tid == 0) s += ev[W];
      #pragma unroll
      for (int off = 32; off > 0; off >>= 1) s += __shfl_xor(s, off, 64);
      if (tid == 0) Sev_s = s;
    }
    __syncthreads();
    // ---- row finalize: eu_i = mu_i / rowsum_i ----
    if (tid < W) {
      float s = 0.0f;
      #pragma unroll
      for (int r = 0; r < 32; ++r) s += part.f[r][tid];
      s += ephi_s * ev[W];
      eu[tid] = inv2w / s;
    } else if (tid == W) {
      eu[W] = 0.5f / (ephi_s * Sev_s);
    }
    __syncthreads();
  }

  // ---- finale: P[i][j] = E*eu_i*ev_j*2W on the WxW block; argmax + 3-window ----
  if (tid < W) { win[tid][0] = 0.0f; win[tid][1] = 0.0f; win[tid][2] = 0.0f; }
  {
    #pragma unroll
    for (int a = 0; a < 8; ++a) {
      float m = -1.0f; int mj = 0;
      #pragma unroll
      for (int b = 0; b < 8; ++b) {
        float vv = E[a][b] * ev[tc * 8 + b];  // eu_i*2W constant per row: drop
        if (vv > m) { m = vv; mj = tc * 8 + b; }   // strict > keeps first max
      }
      // pack (value, first-index-wins) for u64 max-reduce; values > 0 so
      // float bit pattern is order-preserving.
      part.a[tc][tr * 8 + a] =
          (((unsigned long long)__float_as_uint(m)) << 32) |
          (unsigned)(65535 - mj);
    }
  }
  __syncthreads();
  if (tid < W) {
    unsigned long long best = 0ull;
    #pragma unroll
    for (int r = 0; r < 32; ++r) {
      unsigned long long k = part.a[r][tid];
      best = (k > best) ? k : best;
    }
    jmax[tid] = 65535 - (int)(best & 0xffffffffull);
  }
  __syncthreads();
  // window scatter: the unique owner of column j writes P[i][j]
  {
    #pragma unroll
    for (int a = 0; a < 8; ++a) {
      int i  = tr * 8 + a;
      int jm = jmax[i];
      #pragma unroll
      for (int k = 0; k < 3; ++k) {
        int j = jm - 1 + k;
        int b = j - tc * 8;
        if (b >= 0 && b < 8) {
          win[i][k] = E[a][b] * ev[j] * eu[i] * (2.0f * W);
        }
      }
    }
  }
  __syncthreads();
  if (tid < W) {
    const int i  = tid;
    const int jm = jmax[i];
    float w0 = win[i][0], w1 = win[i][1], w2 = win[i][2];
    float norm0 = w0 + w1 + w2;
    float norm  = (norm0 < 0.1f) ? 1.0f : norm0;
    // pos_shift padded with zero cols; out-of-range taps have w==0 anyway
    float p0 = fmaxf((float)(i - (jm - 1)), 0.0f);
    float p1 = fmaxf((float)(i - jm),       0.0f);
    float p2 = fmaxf((float)(i - (jm + 1)), 0.0f);
    float disp = (w0 / norm) * p0 + (w1 / norm) * p1 + (w2 / norm) * p2;
    float occ  = 1.0f - norm;
    out[(size_t)bid * W + i] = disp;
    out[(size_t)nh * W + (size_t)bid * W + i] = occ;
  }
}

} // namespace

extern "C" void kernel_launch(void* const* d_in, const int* in_sizes, int n_in,
                              void* d_out, int out_size, void* d_ws, size_t ws_size,
                              hipStream_t stream) {
  (void)n_in; (void)d_ws; (void)ws_size; (void)out_size;
  const float* attn = (const float*)d_in[0];
  const float* phi  = (const float*)d_in[1];
  float* out = (float*)d_out;
  const int nh = in_sizes[0] / (W * W);   // 4*120 = 480 matrices
  sinkhorn_disp_kernel<<<dim3(nh), dim3(1024), 0, stream>>>(attn, phi, out, nh);
}

// Round 2
// 308.398 us; speedup vs baseline: 1.1717x; 1.1717x over previous
//
#include <hip/hip_runtime.h>
#include <cstdint>

namespace {

constexpr int W = 256;
constexpr int ITERS = 10;

// One block per (n,h) matrix. 1024 threads; thread (tr=tid>>5, tc=tid&31)
// owns the 8x8 tile rows [8tr,8tr+8) x cols [8tc,8tc+8) of E = exp(attn),
// kept in registers for all 10 Sinkhorn iterations (exp-domain recursion:
// no transcendentals after the initial exp).
//
// R2 fix: ALL accesses to E[][] use compile-time indices (the R1 version had
// one runtime-indexed read in the window scatter, which demoted E to scratch:
// VGPR_Count=64, WRITE_SIZE=187MB, 237us. Dynamic indices only touch LDS.)
__global__ __launch_bounds__(1024, 4) void sinkhorn_disp_kernel(
    const float* __restrict__ attn,
    const float* __restrict__ phi_p,
    float* __restrict__ out,
    int nh)
{
  // partial buffer: 32 partials per column/row. float stride 260 so that the
  // two tr-halves of a wave hit disjoint bank sets on ds_write_b128.
  __shared__ union {
    float f[32][260];                 // GEMV partials (33,280 B)
    unsigned long long a[32][257];    // argmax partials (65,792 B)
  } part;
  __shared__ float eu[W + 1];
  __shared__ float ev[W + 1];
  __shared__ float win[W][4];
  __shared__ int   jmax[W];
  __shared__ float Seu_s, Sev_s, ephi_s;

  const int tid = threadIdx.x;
  const int tc  = tid & 31;
  const int tr  = tid >> 5;
  const int bid = blockIdx.x;

  // ---- load + exp (the only big HBM traffic: 256 KB/block) ----
  float E[8][8];
  {
    const float* src = attn + (size_t)bid * (W * W) + (size_t)(tr * 8) * W + tc * 8;
    #pragma unroll
    for (int a = 0; a < 8; ++a) {
      float4 x0 = *(const float4*)(src + a * W);
      float4 x1 = *(const float4*)(src + a * W + 4);
      E[a][0] = __expf(x0.x); E[a][1] = __expf(x0.y);
      E[a][2] = __expf(x0.z); E[a][3] = __expf(x0.w);
      E[a][4] = __expf(x1.x); E[a][5] = __expf(x1.y);
      E[a][6] = __expf(x1.z); E[a][7] = __expf(x1.w);
    }
  }
  if (tid <= W) eu[tid] = 1.0f;          // u0 = 0  -> eu = 1
  if (tid == 0) ephi_s = __expf(phi_p[0]);
  __syncthreads();

  const float inv2w = 1.0f / (2.0f * W); // mu_i = nu_i = 1/(2W) for i<W; 0.5 at dustbin

  for (int it = 0; it < ITERS; ++it) {
    // ---- column pass partials: cp[b] = sum_a E[a][b] * eu[8tr+a] ----
    {
      float4 u0 = *(const float4*)&eu[tr * 8];
      float4 u1 = *(const float4*)&eu[tr * 8 + 4];
      float ul[8] = {u0.x, u0.y, u0.z, u0.w, u1.x, u1.y, u1.z, u1.w};
      float cp[8];
      #pragma unroll
      for (int b = 0; b < 8; ++b) cp[b] = 0.0f;
      #pragma unroll
      for (int a = 0; a < 8; ++a) {
        #pragma unroll
        for (int b = 0; b < 8; ++b) cp[b] = __builtin_fmaf(E[a][b], ul[a], cp[b]);
      }
      float4* dst = (float4*)&part.f[tr][tc * 8];
      dst[0] = make_float4(cp[0], cp[1], cp[2], cp[3]);
      dst[1] = make_float4(cp[4], cp[5], cp[6], cp[7]);
    }
    // wave 0 (concurrently): Seu = sum_{i<=W} eu_i (for dustbin column)
    if (tid < 64) {
      float s = eu[tid] + eu[tid + 64] + eu[tid + 128] + eu[tid + 192];
      if (tid == 0) s += eu[W];
      #pragma unroll
      for (int off = 32; off > 0; off >>= 1) s += __shfl_xor(s, off, 64);
      if (tid == 0) Seu_s = s;
    }
    __syncthreads();
    // ---- column finalize: ev_j = nu_j / colsum_j ----
    if (tid < W) {
      float s = 0.0f;
      #pragma unroll
      for (int r = 0; r < 32; ++r) s += part.f[r][tid];   // stride-1, conflict-free
      s += ephi_s * eu[W];                                // dustbin row contribution
      ev[tid] = inv2w / s;
    } else if (tid == W) {
      ev[W] = 0.5f / (ephi_s * Seu_s);                    // dustbin column
    }
    __syncthreads();
    // ---- row pass partials: rp[a] = sum_b E[a][b] * ev[8tc+b] ----
    {
      float4 v0 = *(const float4*)&ev[tc * 8];
      float4 v1 = *(const float4*)&ev[tc * 8 + 4];
      float vl[8] = {v0.x, v0.y, v0.z, v0.w, v1.x, v1.y, v1.z, v1.w};
      float rp[8];
      #pragma unroll
      for (int a = 0; a < 8; ++a) rp[a] = 0.0f;
      #pragma unroll
      for (int b = 0; b < 8; ++b) {
        #pragma unroll
        for (int a = 0; a < 8; ++a) rp[a] = __builtin_fmaf(E[a][b], vl[b], rp[a]);
      }
      float4* dst = (float4*)&part.f[tc][tr * 8];
      dst[0] = make_float4(rp[0], rp[1], rp[2], rp[3]);
      dst[1] = make_float4(rp[4], rp[5], rp[6], rp[7]);
    }
    // wave 0: Sev = sum_{j<=W} ev_j (for dustbin row)
    if (tid < 64) {
      float s = ev[tid] + ev[tid + 64] + ev[tid + 128] + ev[tid + 192];
      if (tid == 0) s += ev[W];
      #pragma unroll
      for (int off = 32; off > 0; off >>= 1) s += __shfl_xor(s, off, 64);
      if (tid == 0) Sev_s = s;
    }
    __syncthreads();
    // ---- row finalize: eu_i = mu_i / rowsum_i ----
    if (tid < W) {
      float s = 0.0f;
      #pragma unroll
      for (int r = 0; r < 32; ++r) s += part.f[r][tid];
      s += ephi_s * ev[W];
      eu[tid] = inv2w / s;
    } else if (tid == W) {
      eu[W] = 0.5f / (ephi_s * Sev_s);
    }
    __syncthreads();
  }

  // ---- finale: P[i][j] = E*eu_i*ev_j*2W on the WxW block; argmax + 3-window ----
  if (tid < W) { win[tid][0] = 0.0f; win[tid][1] = 0.0f; win[tid][2] = 0.0f; }
  float vl[8];
  {
    float4 v0 = *(const float4*)&ev[tc * 8];
    float4 v1 = *(const float4*)&ev[tc * 8 + 4];
    vl[0] = v0.x; vl[1] = v0.y; vl[2] = v0.z; vl[3] = v0.w;
    vl[4] = v1.x; vl[5] = v1.y; vl[6] = v1.z; vl[7] = v1.w;
  }
  {
    #pragma unroll
    for (int a = 0; a < 8; ++a) {
      float m = -1.0f; int mj = 0;
      #pragma unroll
      for (int b = 0; b < 8; ++b) {
        float vv = E[a][b] * vl[b];           // eu_i*2W constant per row: drop
        if (vv > m) { m = vv; mj = tc * 8 + b; }   // strict > keeps first max
      }
      // pack (value, first-index-wins) for u64 max-reduce; values > 0 so
      // float bit pattern is order-preserving.
      part.a[tc][tr * 8 + a] =
          (((unsigned long long)__float_as_uint(m)) << 32) |
          (unsigned)(65535 - mj);
    }
  }
  __syncthreads();
  if (tid < W) {
    unsigned long long best = 0ull;
    #pragma unroll
    for (int r = 0; r < 32; ++r) {
      unsigned long long k = part.a[r][tid];
      best = (k > best) ? k : best;
    }
    jmax[tid] = 65535 - (int)(best & 0xffffffffull);
  }
  __syncthreads();
  // window scatter: the unique owner of column j writes P[i][j].
  // NOTE: b is a compile-time constant here; the dynamic index k hits LDS only.
  {
    float4 u0 = *(const float4*)&eu[tr * 8];
    float4 u1 = *(const float4*)&eu[tr * 8 + 4];
    float ul[8] = {u0.x, u0.y, u0.z, u0.w, u1.x, u1.y, u1.z, u1.w};
    #pragma unroll
    for (int a = 0; a < 8; ++a) {
      int i  = tr * 8 + a;
      int jm = jmax[i];
      #pragma unroll
      for (int b = 0; b < 8; ++b) {
        int k = (tc * 8 + b) - (jm - 1);
        if (k >= 0 && k < 3) {
          win[i][k] = E[a][b] * vl[b] * ul[a] * (2.0f * W);
        }
      }
    }
  }
  __syncthreads();
  if (tid < W) {
    const int i  = tid;
    const int jm = jmax[i];
    float w0 = win[i][0], w1 = win[i][1], w2 = win[i][2];
    float norm0 = w0 + w1 + w2;
    float norm  = (norm0 < 0.1f) ? 1.0f : norm0;
    // pos_shift padded with zero cols; out-of-range taps have w==0 anyway
    float p0 = fmaxf((float)(i - (jm - 1)), 0.0f);
    float p1 = fmaxf((float)(i - jm),       0.0f);
    float p2 = fmaxf((float)(i - (jm + 1)), 0.0f);
    float disp = (w0 / norm) * p0 + (w1 / norm) * p1 + (w2 / norm) * p2;
    float occ  = 1.0f - norm;
    out[(size_t)bid * W + i] = disp;
    out[(size_t)nh * W + (size_t)bid * W + i] = occ;
  }
}

} // namespace

extern "C" void kernel_launch(void* const* d_in, const int* in_sizes, int n_in,
                              void* d_out, int out_size, void* d_ws, size_t ws_size,
                              hipStream_t stream) {
  (void)n_in; (void)d_ws; (void)ws_size; (void)out_size;
  const float* attn = (const float*)d_in[0];
  const float* phi  = (const float*)d_in[1];
  float* out = (float*)d_out;
  const int nh = in_sizes[0] / (W * W);   // 4*120 = 480 matrices
  sinkhorn_disp_kernel<<<dim3(nh), dim3(1024), 0, stream>>>(attn, phi, out, nh);
}

// Round 3
// 307.569 us; speedup vs baseline: 1.1749x; 1.0027x over previous
//
#include <hip/hip_runtime.h>
#include <cstdint>

namespace {

constexpr int W = 256;
constexpr int ITERS = 10;

// One block per (n,h) matrix. 1024 threads; thread (tr=tid>>5, tc=tid&31)
// owns the 8x8 tile rows [8tr,8tr+8) x cols [8tc,8tc+8) of E = exp(attn),
// kept in registers for all 10 Sinkhorn iterations (exp-domain recursion:
// no transcendentals after the initial exp).
//
// R2 fix: ALL accesses to E[][] use compile-time indices.
// R3 fix: amdgpu_waves_per_eu(4,4) — __launch_bounds__(1024,4) only sets a
// MINIMUM occupancy; the backend spilled half of E to scratch to reach
// 8 waves/EU (VGPR_Count=64, WRITE_SIZE=58MB). Pinning max=4 gives the
// allocator the full 128-VGPR budget so E(64 regs) stays resident.
__global__ __attribute__((amdgpu_flat_work_group_size(1024, 1024),
                          amdgpu_waves_per_eu(4, 4)))
void sinkhorn_disp_kernel(
    const float* __restrict__ attn,
    const float* __restrict__ phi_p,
    float* __restrict__ out,
    int nh)
{
  // partial buffer: 32 partials per column/row. float stride 260 so that the
  // two tr-halves of a wave hit disjoint bank sets on ds_write_b128.
  __shared__ union {
    float f[32][260];                 // GEMV partials (33,280 B)
    unsigned long long a[32][257];    // argmax partials (65,792 B)
  } part;
  __shared__ float eu[W + 1];
  __shared__ float ev[W + 1];
  __shared__ float win[W][4];
  __shared__ int   jmax[W];
  __shared__ float Seu_s, Sev_s, ephi_s;

  const int tid = threadIdx.x;
  const int tc  = tid & 31;
  const int tr  = tid >> 5;
  const int bid = blockIdx.x;

  // ---- load + exp (the only big HBM traffic: 256 KB/block) ----
  float E[8][8];
  {
    const float* src = attn + (size_t)bid * (W * W) + (size_t)(tr * 8) * W + tc * 8;
    #pragma unroll
    for (int a = 0; a < 8; ++a) {
      float4 x0 = *(const float4*)(src + a * W);
      float4 x1 = *(const float4*)(src + a * W + 4);
      E[a][0] = __expf(x0.x); E[a][1] = __expf(x0.y);
      E[a][2] = __expf(x0.z); E[a][3] = __expf(x0.w);
      E[a][4] = __expf(x1.x); E[a][5] = __expf(x1.y);
      E[a][6] = __expf(x1.z); E[a][7] = __expf(x1.w);
    }
  }
  if (tid <= W) eu[tid] = 1.0f;          // u0 = 0  -> eu = 1
  if (tid == 0) ephi_s = __expf(phi_p[0]);
  __syncthreads();

  const float inv2w = 1.0f / (2.0f * W); // mu_i = nu_i = 1/(2W) for i<W; 0.5 at dustbin

  for (int it = 0; it < ITERS; ++it) {
    // ---- column pass partials: cp[b] = sum_a E[a][b] * eu[8tr+a] ----
    {
      float4 u0 = *(const float4*)&eu[tr * 8];
      float4 u1 = *(const float4*)&eu[tr * 8 + 4];
      float ul[8] = {u0.x, u0.y, u0.z, u0.w, u1.x, u1.y, u1.z, u1.w};
      float cp[8];
      #pragma unroll
      for (int b = 0; b < 8; ++b) cp[b] = 0.0f;
      #pragma unroll
      for (int a = 0; a < 8; ++a) {
        #pragma unroll
        for (int b = 0; b < 8; ++b) cp[b] = __builtin_fmaf(E[a][b], ul[a], cp[b]);
      }
      float4* dst = (float4*)&part.f[tr][tc * 8];
      dst[0] = make_float4(cp[0], cp[1], cp[2], cp[3]);
      dst[1] = make_float4(cp[4], cp[5], cp[6], cp[7]);
    }
    // wave 0 (concurrently): Seu = sum_{i<=W} eu_i (for dustbin column)
    if (tid < 64) {
      float s = eu[tid] + eu[tid + 64] + eu[tid + 128] + eu[tid + 192];
      if (tid == 0) s += eu[W];
      #pragma unroll
      for (int off = 32; off > 0; off >>= 1) s += __shfl_xor(s, off, 64);
      if (tid == 0) Seu_s = s;
    }
    __syncthreads();
    // ---- column finalize: ev_j = nu_j / colsum_j ----
    if (tid < W) {
      float s = 0.0f;
      #pragma unroll
      for (int r = 0; r < 32; ++r) s += part.f[r][tid];   // stride-1, conflict-free
      s += ephi_s * eu[W];                                // dustbin row contribution
      ev[tid] = inv2w / s;
    } else if (tid == W) {
      ev[W] = 0.5f / (ephi_s * Seu_s);                    // dustbin column
    }
    __syncthreads();
    // ---- row pass partials: rp[a] = sum_b E[a][b] * ev[8tc+b] ----
    {
      float4 v0 = *(const float4*)&ev[tc * 8];
      float4 v1 = *(const float4*)&ev[tc * 8 + 4];
      float vl[8] = {v0.x, v0.y, v0.z, v0.w, v1.x, v1.y, v1.z, v1.w};
      float rp[8];
      #pragma unroll
      for (int a = 0; a < 8; ++a) rp[a] = 0.0f;
      #pragma unroll
      for (int b = 0; b < 8; ++b) {
        #pragma unroll
        for (int a = 0; a < 8; ++a) rp[a] = __builtin_fmaf(E[a][b], vl[b], rp[a]);
      }
      float4* dst = (float4*)&part.f[tc][tr * 8];
      dst[0] = make_float4(rp[0], rp[1], rp[2], rp[3]);
      dst[1] = make_float4(rp[4], rp[5], rp[6], rp[7]);
    }
    // wave 0: Sev = sum_{j<=W} ev_j (for dustbin row)
    if (tid < 64) {
      float s = ev[tid] + ev[tid + 64] + ev[tid + 128] + ev[tid + 192];
      if (tid == 0) s += ev[W];
      #pragma unroll
      for (int off = 32; off > 0; off >>= 1) s += __shfl_xor(s, off, 64);
      if (tid == 0) Sev_s = s;
    }
    __syncthreads();
    // ---- row finalize: eu_i = mu_i / rowsum_i ----
    if (tid < W) {
      float s = 0.0f;
      #pragma unroll
      for (int r = 0; r < 32; ++r) s += part.f[r][tid];
      s += ephi_s * ev[W];
      eu[tid] = inv2w / s;
    } else if (tid == W) {
      eu[W] = 0.5f / (ephi_s * Sev_s);
    }
    __syncthreads();
  }

  // ---- finale: P[i][j] = E*eu_i*ev_j*2W on the WxW block; argmax + 3-window ----
  if (tid < W) { win[tid][0] = 0.0f; win[tid][1] = 0.0f; win[tid][2] = 0.0f; }
  float vl[8];
  {
    float4 v0 = *(const float4*)&ev[tc * 8];
    float4 v1 = *(const float4*)&ev[tc * 8 + 4];
    vl[0] = v0.x; vl[1] = v0.y; vl[2] = v0.z; vl[3] = v0.w;
    vl[4] = v1.x; vl[5] = v1.y; vl[6] = v1.z; vl[7] = v1.w;
  }
  {
    #pragma unroll
    for (int a = 0; a < 8; ++a) {
      float m = -1.0f; int mj = 0;
      #pragma unroll
      for (int b = 0; b < 8; ++b) {
        float vv = E[a][b] * vl[b];           // eu_i*2W constant per row: drop
        if (vv > m) { m = vv; mj = tc * 8 + b; }   // strict > keeps first max
      }
      // pack (value, first-index-wins) for u64 max-reduce; values > 0 so
      // float bit pattern is order-preserving.
      part.a[tc][tr * 8 + a] =
          (((unsigned long long)__float_as_uint(m)) << 32) |
          (unsigned)(65535 - mj);
    }
  }
  __syncthreads();
  if (tid < W) {
    unsigned long long best = 0ull;
    #pragma unroll
    for (int r = 0; r < 32; ++r) {
      unsigned long long k = part.a[r][tid];
      best = (k > best) ? k : best;
    }
    jmax[tid] = 65535 - (int)(best & 0xffffffffull);
  }
  __syncthreads();
  // window scatter: the unique owner of column j writes P[i][j].
  // NOTE: b is a compile-time constant here; the dynamic index k hits LDS only.
  {
    float4 u0 = *(const float4*)&eu[tr * 8];
    float4 u1 = *(const float4*)&eu[tr * 8 + 4];
    float ul[8] = {u0.x, u0.y, u0.z, u0.w, u1.x, u1.y, u1.z, u1.w};
    #pragma unroll
    for (int a = 0; a < 8; ++a) {
      int i  = tr * 8 + a;
      int jm = jmax[i];
      #pragma unroll
      for (int b = 0; b < 8; ++b) {
        int k = (tc * 8 + b) - (jm - 1);
        if (k >= 0 && k < 3) {
          win[i][k] = E[a][b] * vl[b] * ul[a] * (2.0f * W);
        }
      }
    }
  }
  __syncthreads();
  if (tid < W) {
    const int i  = tid;
    const int jm = jmax[i];
    float w0 = win[i][0], w1 = win[i][1], w2 = win[i][2];
    float norm0 = w0 + w1 + w2;
    float norm  = (norm0 < 0.1f) ? 1.0f : norm0;
    // pos_shift padded with zero cols; out-of-range taps have w==0 anyway
    float p0 = fmaxf((float)(i - (jm - 1)), 0.0f);
    float p1 = fmaxf((float)(i - jm),       0.0f);
    float p2 = fmaxf((float)(i - (jm + 1)), 0.0f);
    float disp = (w0 / norm) * p0 + (w1 / norm) * p1 + (w2 / norm) * p2;
    float occ  = 1.0f - norm;
    out[(size_t)bid * W + i] = disp;
    out[(size_t)nh * W + (size_t)bid * W + i] = occ;
  }
}

} // namespace

extern "C" void kernel_launch(void* const* d_in, const int* in_sizes, int n_in,
                              void* d_out, int out_size, void* d_ws, size_t ws_size,
                              hipStream_t stream) {
  (void)n_in; (void)d_ws; (void)ws_size; (void)out_size;
  const float* attn = (const float*)d_in[0];
  const float* phi  = (const float*)d_in[1];
  float* out = (float*)d_out;
  const int nh = in_sizes[0] / (W * W);   // 4*120 = 480 matrices
  sinkhorn_disp_kernel<<<dim3(nh), dim3(1024), 0, stream>>>(attn, phi, out, nh);
}